// Round 1
// baseline (657.969 us; speedup 1.0000x reference)
//
#include <hip/hip_runtime.h>

// LogSqrt2Quantizer: out[i] = F[bucket(x[i])], plus out[n] = s_x.
//
// bucket: v = rintf(x*65536)+66 (integer-valued fp32 in [66,65602]);
//   octave e = rawexp(v)-133 in [0,10]; +1 if v > 2^(e_real+0.5), i.e.
//   mantissa_field(v) > floor((sqrt(2)-1)*2^23) = 3474675. Exact for integer v.
// F[idx] = lut[qtab[idx]] * s_x, qtab derived by emulating the reference's
//   float32 y/scale -> round-half-even chain exactly:
//   idx 0..10 (r=-6..-16) -> q = {15,14,12,10,9,8,6,4,3,2,0}
//   packed as nibbles: 0x0234689ACEF.
//
// This revision vs previous (623 us):
//  - grid-stride at 2048 blocks (256 CU x 8 blocks/CU): LDS table setup
//    amortized 48x instead of once per 98K blocks.
//  - nontemporal stores: out is write-once/never-read (re-poisoned each
//    iteration) -> no-allocate stores keep input lines resident in L3
//    across graph replays (input 402MB vs 256MB L3: partial residency
//    cuts HBM FETCH_SIZE).

typedef float f32x4 __attribute__((ext_vector_type(4)));

__device__ __forceinline__ unsigned bucket_of(float xx) {
    float v = rintf(xx * 65536.0f) + 66.0f;      // exact: *2^16 is exp shift
    unsigned b = __float_as_uint(v);
    unsigned idx = (b >> 23) - 133u;             // octave 0..10
    idx += (b & 0x7FFFFFu) > 3474675u;           // upper half-octave
    return idx;
}

__global__ __launch_bounds__(256) void logq_map_kernel(
    const float* __restrict__ x,
    const float* __restrict__ s_x,
    const float* __restrict__ lut,
    float* __restrict__ out,
    int n, int n4)
{
    __shared__ float sF[16];
    const int t = threadIdx.x;
    if (t < 11) {
        int q = (int)((0x0234689ACEFULL >> (4 * t)) & 0xFULL);
        sF[t] = lut[q] * s_x[0];
    }
    __syncthreads();

    const int stride = gridDim.x * 256;
    for (int i = blockIdx.x * 256 + t; i < n4; i += stride) {
        const int base = i * 4;
        if (base + 3 < n) {
            const f32x4 xv = *(const f32x4*)(x + base);
            f32x4 ov;
            ov.x = sF[bucket_of(xv.x)];
            ov.y = sF[bucket_of(xv.y)];
            ov.z = sF[bucket_of(xv.z)];
            ov.w = sF[bucket_of(xv.w)];
            __builtin_nontemporal_store(ov, (f32x4*)(out + base));
        } else {
            // tail (n % 4 != 0) — not hit for this problem size, kept for safety
            for (int j = base; j < n; ++j) out[j] = sF[bucket_of(x[j])];
        }
    }

    if (blockIdx.x == 0 && t == 0) out[n] = s_x[0];  // second tuple element
}

extern "C" void kernel_launch(void* const* d_in, const int* in_sizes, int n_in,
                              void* d_out, int out_size, void* d_ws, size_t ws_size,
                              hipStream_t stream) {
    const float* x   = (const float*)d_in[0];
    const float* s_x = (const float*)d_in[1];
    const float* lut = (const float*)d_in[5];
    float* out = (float*)d_out;
    const int n = in_sizes[0];

    const int n4 = (n + 3) / 4;
    int blocks = (n4 + 255) / 256;
    if (blocks > 2048) blocks = 2048;   // 256 CU x 8 wg/CU, grid-stride the rest
    logq_map_kernel<<<blocks, 256, 0, stream>>>(x, s_x, lut, out, n, n4);
}

// Round 3
// 643.832 us; speedup vs baseline: 1.0220x; 1.0220x over previous
//
#include <hip/hip_runtime.h>

// LogSqrt2Quantizer: out[i] = F[bucket(x[i])], plus out[n] = s_x.
//
// bucket: v = rintf(x*65536)+66 (integer-valued fp32 in [66,65602]);
//   octave e = rawexp(v)-133 in [0,10]; +1 if v > 2^(e_real+0.5), i.e.
//   mantissa_field(v) > floor((sqrt(2)-1)*2^23) = 3474675. Exact for integer v.
// F[idx] = lut[qtab[idx]] * s_x, qtab derived by emulating the reference's
//   float32 y/scale -> round-half-even chain exactly:
//   idx 0..10 (r=-6..-16) -> q = {15,14,12,10,9,8,6,4,3,2,0}
//   packed as nibbles: 0x0234689ACEF.
//
// Round-2 attribution experiment (resubmitted after container failure):
// Round 1 (grid-stride + NT stores) regressed 623 -> 658 us. Theory: NT
// stores were the harm — the harness fill (1.6 GB) thrashes L3 between
// iterations, so there was no input residency to protect, and NT forced the
// 402 MB output write-through inside the kernel instead of letting
// write-back drain overlap the next fill. This round: NT store reverted to
// plain store; grid-stride kept UNCHANGED for clean A/B.

typedef float f32x4 __attribute__((ext_vector_type(4)));

__device__ __forceinline__ unsigned bucket_of(float xx) {
    float v = rintf(xx * 65536.0f) + 66.0f;      // exact: *2^16 is exp shift
    unsigned b = __float_as_uint(v);
    unsigned idx = (b >> 23) - 133u;             // octave 0..10
    idx += (b & 0x7FFFFFu) > 3474675u;           // upper half-octave
    return idx;
}

__global__ __launch_bounds__(256) void logq_map_kernel(
    const float* __restrict__ x,
    const float* __restrict__ s_x,
    const float* __restrict__ lut,
    float* __restrict__ out,
    int n, int n4)
{
    __shared__ float sF[16];
    const int t = threadIdx.x;
    if (t < 11) {
        int q = (int)((0x0234689ACEFULL >> (4 * t)) & 0xFULL);
        sF[t] = lut[q] * s_x[0];
    }
    __syncthreads();

    const int stride = gridDim.x * 256;
    for (int i = blockIdx.x * 256 + t; i < n4; i += stride) {
        const int base = i * 4;
        if (base + 3 < n) {
            const f32x4 xv = *(const f32x4*)(x + base);
            f32x4 ov;
            ov.x = sF[bucket_of(xv.x)];
            ov.y = sF[bucket_of(xv.y)];
            ov.z = sF[bucket_of(xv.z)];
            ov.w = sF[bucket_of(xv.w)];
            *(f32x4*)(out + base) = ov;           // plain write-back store
        } else {
            // tail (n % 4 != 0) — not hit for this problem size, kept for safety
            for (int j = base; j < n; ++j) out[j] = sF[bucket_of(x[j])];
        }
    }

    if (blockIdx.x == 0 && t == 0) out[n] = s_x[0];  // second tuple element
}

extern "C" void kernel_launch(void* const* d_in, const int* in_sizes, int n_in,
                              void* d_out, int out_size, void* d_ws, size_t ws_size,
                              hipStream_t stream) {
    const float* x   = (const float*)d_in[0];
    const float* s_x = (const float*)d_in[1];
    const float* lut = (const float*)d_in[5];
    float* out = (float*)d_out;
    const int n = in_sizes[0];

    const int n4 = (n + 3) / 4;
    int blocks = (n4 + 255) / 256;
    if (blocks > 2048) blocks = 2048;   // 256 CU x 8 wg/CU, grid-stride the rest
    logq_map_kernel<<<blocks, 256, 0, stream>>>(x, s_x, lut, out, n, n4);
}

// Round 4
// 622.253 us; speedup vs baseline: 1.0574x; 1.0347x over previous
//
#include <hip/hip_runtime.h>

// LogSqrt2Quantizer: out[i] = F[bucket(x[i])], plus out[n] = s_x.
//
// bucket: v = rintf(x*65536)+66 (integer-valued fp32 in [66,65602]);
//   octave e = rawexp(v)-133 in [0,10]; +1 if v > 2^(e_real+0.5), i.e.
//   mantissa_field(v) > floor((sqrt(2)-1)*2^23) = 3474675. Exact for integer v.
// F[idx] = lut[qtab[idx]] * s_x, qtab derived by emulating the reference's
//   float32 y/scale -> round-half-even chain exactly (odd |r| hit exact .5
//   ties in fp32; half-even resolves them):
//   idx 0..10 (r=-6..-16) -> q = {15,14,12,10,9,8,6,4,3,2,0}
//   packed as nibbles: 0x0234689ACEF.
//
// REVERT to Round-0 form (best measured: 623.5 us). Attribution matrix:
//   R0 per-block + plain store : 623.5  <- best
//   R1 grid-stride + NT store  : 658.0  (NT: no L3 residency to protect —
//                                harness fill thrashes L3 every iter; NT
//                                forces sync write-through in-kernel)
//   R3 grid-stride + plain     : 643.8  (grid-stride: adds loop overhead +
//                                long-lived waves; per-block straight-line
//                                code gets max MLP from the dispatch queue)
// Kernel component ~111 us for 805 MB = ~7.3 TB/s effective — beyond the
// 6.3 TB/s copy ceiling (store drain overlaps next fill). At roofline.

__device__ __forceinline__ unsigned bucket_of(float xx) {
    float v = rintf(xx * 65536.0f) + 66.0f;      // exact: *2^16 is exp shift
    unsigned b = __float_as_uint(v);
    unsigned idx = (b >> 23) - 133u;             // octave 0..10
    idx += (b & 0x7FFFFFu) > 3474675u;           // upper half-octave
    return idx;
}

__global__ __launch_bounds__(256) void logq_map_kernel(
    const float* __restrict__ x,
    const float* __restrict__ s_x,
    const float* __restrict__ lut,
    float* __restrict__ out,
    int n)
{
    __shared__ float sF[11];
    const int t = threadIdx.x;
    if (t < 11) {
        int q = (int)((0x0234689ACEFULL >> (4 * t)) & 0xFULL);
        sF[t] = lut[q] * s_x[0];
    }
    __syncthreads();

    const int i = blockIdx.x * 256 + t;
    const int base = i * 4;

    if (base + 3 < n) {
        const float4 xv = *(const float4*)(x + base);
        float4 ov;
        ov.x = sF[bucket_of(xv.x)];
        ov.y = sF[bucket_of(xv.y)];
        ov.z = sF[bucket_of(xv.z)];
        ov.w = sF[bucket_of(xv.w)];
        *(float4*)(out + base) = ov;
    } else if (base < n) {
        for (int j = base; j < n; ++j) out[j] = sF[bucket_of(x[j])];
    }

    if (i == 0) out[n] = s_x[0];   // second tuple element: s_x passthrough
}

extern "C" void kernel_launch(void* const* d_in, const int* in_sizes, int n_in,
                              void* d_out, int out_size, void* d_ws, size_t ws_size,
                              hipStream_t stream) {
    const float* x   = (const float*)d_in[0];
    const float* s_x = (const float*)d_in[1];
    const float* lut = (const float*)d_in[5];
    float* out = (float*)d_out;
    const int n = in_sizes[0];

    const int n4     = (n + 3) / 4;
    const int blocks = (n4 + 255) / 256;
    logq_map_kernel<<<blocks, 256, 0, stream>>>(x, s_x, lut, out, n);
}